// Round 7
// baseline (316.161 us; speedup 1.0000x reference)
//
#include <hip/hip_runtime.h>

// ---- problem constants ----
#define BSZ 4
#define SEQ 2048
#define DIM 1024
#define NH  16
#define HD  64
#define QT  128   // q rows per block pass (flash)
#define KT  64    // kv rows per tile (flash)
#define PAD 72    // u16 row stride in flash LDS

typedef float v4f __attribute__((ext_vector_type(4)));
typedef short s8v __attribute__((ext_vector_type(8)));
typedef unsigned short u16;
typedef unsigned short u16x8 __attribute__((ext_vector_type(8)));
typedef unsigned short u16x4 __attribute__((ext_vector_type(4)));
typedef unsigned int u32;
typedef unsigned int u32x2 __attribute__((ext_vector_type(2)));
typedef unsigned int u32x4 __attribute__((ext_vector_type(4)));

__device__ __forceinline__ u16 f2bf(float f) {
  u32 u = __builtin_bit_cast(u32, f);
  u32 r = u + 0x7fffu + ((u >> 16) & 1u);  // RNE
  return (u16)(r >> 16);
}
// single v_cvt_pk_bf16_f32 (RNE) — 1 inst for 2 elems
__device__ __forceinline__ u32 cvtpk(float lo, float hi) {
  u32 r; asm("v_cvt_pk_bf16_f32 %0, %1, %2" : "=v"(r) : "v"(lo), "v"(hi)); return r;
}
__device__ __forceinline__ u16 f2bf1(float f) { return (u16)cvtpk(f, f); }
__device__ __forceinline__ float fast_exp2(float x) {
#if __has_builtin(__builtin_amdgcn_exp2f)
  return __builtin_amdgcn_exp2f(x);
#else
  return exp2f(x);
#endif
}
// async global->LDS, 16B per lane; lds ptr must be wave-uniform (HW adds lane*16)
__device__ __forceinline__ void gll16(const u16* g, u16* l) {
  __builtin_amdgcn_global_load_lds((const __attribute__((address_space(1))) void*)g,
                                   (__attribute__((address_space(3))) void*)l, 16, 0, 0);
}

// ---------------- cast x (fp32) -> bf16 ----------------
__global__ __launch_bounds__(256) void cast_bf16_kernel(const float* __restrict__ x,
                                                        u16* __restrict__ o, int n4) {
  int i = blockIdx.x * 256 + threadIdx.x;
  if (i >= n4) return;
  v4f v = reinterpret_cast<const v4f*>(x)[i];
  u16x4 r;
  #pragma unroll
  for (int c = 0; c < 4; c++) r[c] = f2bf(v[c]);
  reinterpret_cast<u16x4*>(o)[i] = r;
}

// ---------------- transpose + cast W[k][n] -> Wt[n][k] bf16 ----------------
// z==0 (Wq) folds in 1/sqrt(HD)*log2(e): Q leaves the QKV GEMM pre-scaled.
__global__ __launch_bounds__(256) void transpose_cast_kernel(const float* __restrict__ W0,
                                                             const float* __restrict__ W1,
                                                             const float* __restrict__ W2,
                                                             const float* __restrict__ W3,
                                                             u16* __restrict__ out) {
  const float* W = blockIdx.z == 0 ? W0 : blockIdx.z == 1 ? W1 : blockIdx.z == 2 ? W2 : W3;
  const float scale = (blockIdx.z == 0) ? 0.18033688011112042f : 1.0f;
  u16* T = out + (size_t)blockIdx.z * DIM * DIM;
  __shared__ float tile[32][33];
  int tx = threadIdx.x & 31, ty = threadIdx.x >> 5;
  int bn = blockIdx.x * 32, bk = blockIdx.y * 32;
  #pragma unroll
  for (int r = 0; r < 4; r++) {
    int k = bk + ty + r * 8;
    tile[ty + r * 8][tx] = W[(size_t)k * DIM + bn + tx];
  }
  __syncthreads();
  #pragma unroll
  for (int r = 0; r < 4; r++) {
    int n = bn + ty + r * 8;
    T[(size_t)n * DIM + bk + tx] = f2bf(tile[tx][ty + r * 8] * scale);
  }
}

// ======== 128x128 GEMM core — faithful m97/m103 structure (874-912 TF measured) ========
// 256 thr = 4 waves (2Mx2N), wave-tile 64x64, acc[4][4]. BK=32, SINGLE 16 KiB LDS
// buffer, plain __syncthreads() (compiler drains vmcnt before s_barrier — the
// known ~20% stall). 3 blocks/CU (launch_bounds(256,3), LDS 16 KiB): implicit
// CROSS-BLOCK overlap (m114) fills each block's barrier/drain stalls — the
// measured mechanism that all 1-block/CU deep pipelines (R1-R6, 570 TF plateau)
// lack. Per K-step: 4 gll16/wave (A units 2w,2w+1; B units 2w,2w+1), 8
// ds_read_b128, 16 MFMA.
// LDS unit layout (gll16 lane-linear, conflict-free): 16-row unit u at u*512
// u16; in-unit lane (sR,sC) at sC*128+sR*8. Frag read: fi*512+quad*128+l16*8.

#define GEMM128_CORE()                                                            \
  __shared__ u16 As[4096];                                                        \
  __shared__ u16 Bs[4096];                                                        \
  const int t = threadIdx.x;                                                      \
  const int lane = t & 63, w = t >> 6;                                            \
  const int wm = w >> 1, wn = w & 1;                                              \
  const int quad = lane >> 4, l16 = lane & 15;                                    \
  const int sR = lane & 15, sC = lane >> 4;                                       \
  const u16* Ag0 = A + (size_t)(m0 + w * 32 + sR) * DIM + sC * 8;                 \
  const u16* Ag1 = Ag0 + (size_t)16 * DIM;                                        \
  const u16* Bg0 = Bt + (size_t)(n0 + w * 32 + sR) * DIM + sC * 8;                \
  const u16* Bg1 = Bg0 + (size_t)16 * DIM;                                        \
  u16* Aw0 = As + (2 * w) * 512;                                                  \
  u16* Aw1 = As + (2 * w + 1) * 512;                                              \
  u16* Bw0 = Bs + (2 * w) * 512;                                                  \
  u16* Bw1 = Bs + (2 * w + 1) * 512;                                              \
  const int aRd = wm * 2048 + quad * 128 + l16 * 8;                               \
  const int bRd = wn * 2048 + quad * 128 + l16 * 8;                               \
  v4f acc[4][4];                                                                  \
  _Pragma("unroll") for (int i = 0; i < 4; i++)                                   \
    _Pragma("unroll") for (int j = 0; j < 4; j++)                                 \
      acc[i][j] = (v4f){0.f, 0.f, 0.f, 0.f};                                      \
  for (int k = 0; k < DIM / 32; ++k) {                                            \
    __syncthreads();                                                              \
    gll16(Ag0 + k * 32, Aw0); gll16(Ag1 + k * 32, Aw1);                           \
    gll16(Bg0 + k * 32, Bw0); gll16(Bg1 + k * 32, Bw1);                           \
    __syncthreads();                                                              \
    s8v af[4], bf[4];                                                             \
    _Pragma("unroll") for (int i = 0; i < 4; i++)                                 \
      af[i] = *(const s8v*)(As + aRd + i * 512);                                  \
    _Pragma("unroll") for (int j = 0; j < 4; j++)                                 \
      bf[j] = *(const s8v*)(Bs + bRd + j * 512);                                  \
    _Pragma("unroll") for (int i = 0; i < 4; i++)                                 \
      _Pragma("unroll") for (int j = 0; j < 4; j++)                               \
        acc[i][j] = __builtin_amdgcn_mfma_f32_16x16x32_bf16(af[i], bf[j],         \
                                                            acc[i][j], 0, 0, 0);  \
  }

// ---------------- fused QKV GEMM; z=0 -> Q (pre-scaled), z=1 -> K, z=2 -> V^T ----------------
// 1536 blocks = 2 clean epochs at 3 blocks/CU. Bijective XCD chunk swizzle
// (1536%8==0): each XCD owns 192 consecutive (z, m-slab, n) tiles; within a
// chunk the 8 n-tiles per m reuse the A-row panel + 2 MB W slab in L2.
__global__ __launch_bounds__(256, 3) void gemm_qkv(const u16* __restrict__ A, const u16* __restrict__ Wt,
                                                   u16* __restrict__ Qb, u16* __restrict__ Kb,
                                                   u16* __restrict__ Vtg) {
  const int bid = blockIdx.x;
  const int swz = (bid & 7) * 192 + (bid >> 3);
  const int z = swz >> 9;            // 3 x 512 blocks
  const int rem = swz & 511;
  const int m0 = (rem >> 3) * 128;   // 64 m-tiles
  const int n0 = (rem & 7) * 128;    // 8 n-tiles
  const u16* Bt = Wt + (size_t)z * DIM * DIM;
  GEMM128_CORE()
  if (z == 2) {
    // write V transposed: Vtg[((b*NH+h)*HD+d)*SEQ + s]
    #pragma unroll
    for (int mi = 0; mi < 4; mi++) {
      #pragma unroll
      for (int ni = 0; ni < 4; ni++) {
        int gm0 = m0 + wm * 64 + mi * 16 + quad * 4;
        int gn = n0 + wn * 64 + ni * 16 + l16;
        int b = gm0 >> 11, s0 = gm0 & (SEQ - 1), hh = gn >> 6, d = gn & (HD - 1);
        u32x2 pw;
        pw[0] = cvtpk(acc[mi][ni][0], acc[mi][ni][1]);
        pw[1] = cvtpk(acc[mi][ni][2], acc[mi][ni][3]);
        *(u16x4*)(Vtg + ((size_t)(b * NH + hh) * HD + d) * SEQ + s0) =
            __builtin_bit_cast(u16x4, pw);
      }
    }
  } else {
    u16* C = (z == 0) ? Qb : Kb;
    #pragma unroll
    for (int mi = 0; mi < 4; mi++) {
      #pragma unroll
      for (int ni = 0; ni < 4; ni++) {
        int gn = n0 + wn * 64 + ni * 16 + l16;
        #pragma unroll
        for (int r = 0; r < 4; r++) {
          int gm = m0 + wm * 64 + mi * 16 + quad * 4 + r;
          C[(size_t)gm * DIM + gn] = f2bf1(acc[mi][ni][r]);
        }
      }
    }
  }
}

// ---------------- projection GEMM: out = ctx * Wo^T + bias (fp32 out) ----------------
// 512 blocks, 3/CU resources -> every CU gets 2 blocks, fully work-conserving.
__global__ __launch_bounds__(256, 3) void gemm_proj(const u16* __restrict__ A, const u16* __restrict__ Bt,
                                                    float* __restrict__ Cf, const float* __restrict__ bias) {
  const int bid = blockIdx.x;
  const int swz = (bid & 7) * 64 + (bid >> 3);  // 512 blocks, bijective
  const int m0 = (swz >> 3) * 128;
  const int n0 = (swz & 7) * 128;
  GEMM128_CORE()
  #pragma unroll
  for (int ni = 0; ni < 4; ni++) {
    int gn = n0 + wn * 64 + ni * 16 + l16;
    float bv = bias[gn];
    #pragma unroll
    for (int mi = 0; mi < 4; mi++) {
      #pragma unroll
      for (int r = 0; r < 4; r++) {
        int gm = m0 + wm * 64 + mi * 16 + quad * 4 + r;
        Cf[(size_t)gm * DIM + gn] = acc[mi][ni][r] + bv;
      }
    }
  }
}

// ---------------- MFMA flash attention (causal), transposed scores ----------------
// S^T = K*Q^T (K rows permuted so P^T registers are directly the PV B-fragment).
// Softmax over kv: 16 in-register values + 2 shfl_xor. O^T = Vt*P^T in C-layout.
// UNPAIRED grid this round: one q-tile per block, grid (NH, 16, BSZ) = 1024
// blocks at 3 blocks/CU (launch_bounds(256,3)) -> work-conserving occupancy
// (was 512 paired blocks over 768 slots = 2/CU). y -> qi interleaves big/small
// (0,15,1,14,...) so the overflow wave isn't all-big blocks.
// cvt_pk P-pack + defer-max (THR=8, exp2 domain) carried (verified R1-R6).
// s_setprio(1) around QK and PV MFMA clusters (T5, attn-proven).
__global__ __launch_bounds__(256, 3) void flash_attn_mfma(const u16* __restrict__ Qb,
                                                          const u16* __restrict__ Kb,
                                                          const u16* __restrict__ Vtg,
                                                          u16* __restrict__ Ob) {
  const int h = blockIdx.x, yy = blockIdx.y, bb = blockIdx.z;
  const int qi = (yy & 1) ? (15 - (yy >> 1)) : (yy >> 1);
  const int t = threadIdx.x;
  const int lane = t & 63, w = t >> 6;
  const int quad = lane >> 4, l16 = lane & 15;

  __shared__ u16 QPs[QT * PAD];  // Q staging, then O^T epilogue bounce
  __shared__ u16 Ks[KT * PAD];   // K tile, rows permuted by pi^-1
  __shared__ u16 Vs[HD * PAD];   // V tile, [d][kv]

  const size_t qkbase = (size_t)bb * SEQ * DIM + h * HD;
  const size_t vbase = ((size_t)bb * NH + h) * (size_t)HD * SEQ;

  const int vrow = t >> 2, scol = (t & 3) * 16;
  const int krow = ((vrow >> 5) + 2 * ((vrow >> 2) & 1)) * 16 + ((vrow >> 3) & 3) * 4 + (vrow & 3);

  const int q0 = qi * QT;
  const int wq = q0 + w * 32;
  const int ntiles = 2 * qi + 2;

  // stage Q (pure copy; scale folded into Wq)
  {
    const int r = t >> 1, c0 = (t & 1) * 32;
    const u16* src = Qb + qkbase + (size_t)(q0 + r) * DIM + c0;
    #pragma unroll
    for (int ch = 0; ch < 4; ch++)
      *(u16x8*)(QPs + r * PAD + c0 + ch * 8) = *(const u16x8*)(src + ch * 8);
  }
  __syncthreads();

  // Q B-fragments: B[n=q][k=d]
  s8v qf[2][2];
  #pragma unroll
  for (int ni = 0; ni < 2; ni++)
    #pragma unroll
    for (int kc = 0; kc < 2; kc++)
      qf[ni][kc] = *(const s8v*)(QPs + (w * 32 + ni * 16 + l16) * PAD + kc * 32 + quad * 8);

  // preload KV tile 0 into registers
  u16x8 kr0, kr1, vr0, vr1;
  {
    const u16* kp = Kb + qkbase + (size_t)vrow * DIM + scol;
    kr0 = *(const u16x8*)kp; kr1 = *(const u16x8*)(kp + 8);
    const u16* vp = Vtg + vbase + (size_t)vrow * SEQ + scol;
    vr0 = *(const u16x8*)vp; vr1 = *(const u16x8*)(vp + 8);
  }

  float mrun[2] = {-1e30f, -1e30f}, lrun[2] = {0.f, 0.f};
  v4f O[4][2];
  #pragma unroll
  for (int di = 0; di < 4; di++)
    #pragma unroll
    for (int ni = 0; ni < 2; ni++) O[di][ni] = (v4f){0.f, 0.f, 0.f, 0.f};

  for (int it = 0; it < ntiles; ++it) {
    const int kv0 = it * KT;
    __syncthreads();
    *(u16x8*)(Ks + krow * PAD + scol) = kr0;
    *(u16x8*)(Ks + krow * PAD + scol + 8) = kr1;
    *(u16x8*)(Vs + vrow * PAD + scol) = vr0;
    *(u16x8*)(Vs + vrow * PAD + scol + 8) = vr1;
    __syncthreads();
    if (it + 1 < ntiles) {  // prefetch next tile (consumed after next barrier)
      const int nkv = kv0 + KT;
      const u16* kp = Kb + qkbase + (size_t)(nkv + vrow) * DIM + scol;
      kr0 = *(const u16x8*)kp; kr1 = *(const u16x8*)(kp + 8);
      const u16* vp = Vtg + vbase + (size_t)vrow * SEQ + nkv + scol;
      vr0 = *(const u16x8*)vp; vr1 = *(const u16x8*)(vp + 8);
    }
    if (kv0 > wq + 31) continue;  // tile fully masked for this wave

    // ---- S^T = K*Q^T : sc[mi][ni], rows kv (permuted), cols q ----
    v4f sc[4][2];
    #pragma unroll
    for (int mi = 0; mi < 4; mi++)
      #pragma unroll
      for (int ni = 0; ni < 2; ni++) sc[mi][ni] = (v4f){0.f, 0.f, 0.f, 0.f};
    __builtin_amdgcn_s_setprio(1);
    #pragma unroll
    for (int kc = 0; kc < 2; kc++) {
      #pragma unroll
      for (int mi = 0; mi < 4; mi++) {
        s8v kf = *(const s8v*)(Ks + (mi * 16 + l16) * PAD + kc * 32 + quad * 8);
        sc[mi][0] = __builtin_amdgcn_mfma_f32_16x16x32_bf16(kf, qf[0][kc], sc[mi][0], 0, 0, 0);
        sc[mi][1] = __builtin_amdgcn_mfma_f32_16x16x32_bf16(kf, qf[1][kc], sc[mi][1], 0, 0, 0);
      }
    }
    __builtin_amdgcn_s_setprio(0);

    // ---- causal mask: kv_g = kv0 + (mi&1)*32 + quad*8 + (mi>>1)*4 + r ----
    if (kv0 + KT > wq) {
      #pragma unroll
      for (int mi = 0; mi < 4; mi++) {
        const int kvb = kv0 + (mi & 1) * 32 + quad * 8 + (mi >> 1) * 4;
        #pragma unroll
        for (int ni = 0; ni < 2; ni++) {
          const int qg = wq + ni * 16 + l16;
          #pragma unroll
          for (int r = 0; r < 4; r++)
            if (kvb + r > qg) sc[mi][ni][r] = -1e30f;
        }
      }
    }

    // ---- online softmax with defer-max (THR=8, exp2 domain) ----
    float mx[2];
    #pragma unroll
    for (int ni = 0; ni < 2; ni++) {
      float m = -1e30f;
      #pragma unroll
      for (int mi = 0; mi < 4; mi++)
        #pragma unroll
        for (int r = 0; r < 4; r++) m = fmaxf(m, sc[mi][ni][r]);
      m = fmaxf(m, __shfl_xor(m, 16, 64));
      m = fmaxf(m, __shfl_xor(m, 32, 64));
      mx[ni] = m;
    }
    const bool defer = __all((mx[0] <= mrun[0] + 8.f) && (mx[1] <= mrun[1] + 8.f));
    if (!defer) {
      float alpha[2];
      #pragma unroll
      for (int ni = 0; ni < 2; ni++) {
        const float mnew = fmaxf(mrun[ni], mx[ni]);
        alpha[ni] = fast_exp2(mrun[ni] - mnew);
        mrun[ni] = mnew;
        lrun[ni] *= alpha[ni];
      }
      #pragma unroll
      for (int di = 0; di < 4; di++)
        #pragma unroll
        for (int ni = 0; ni < 2; ni++)
          #pragma unroll
          for (int r = 0; r < 4; r++) O[di][ni][r] *= alpha[ni];
    }
    #pragma unroll
    for (int ni = 0; ni < 2; ni++) {
      float rsum = 0.f;
      #pragma unroll
      for (int mi = 0; mi < 4; mi++)
        #pragma unroll
        for (int r = 0; r < 4; r++) {
          float p = fast_exp2(sc[mi][ni][r] - mrun[ni]);
          sc[mi][ni][r] = p;
          rsum += p;
        }
      rsum += __shfl_xor(rsum, 16, 64);
      rsum += __shfl_xor(rsum, 32, 64);
      lrun[ni] += rsum;
    }

    // ---- pack P^T as PV B-frag via v_cvt_pk_bf16_f32 ----
    // pf[ni][kc] lanes j: j=0..3 -> sc[kc][ni][j], j=4..7 -> sc[kc+2][ni][j-4]
    s8v pf[2][2];
    #pragma unroll
    for (int ni = 0; ni < 2; ni++)
      #pragma unroll
      for (int kc = 0; kc < 2; kc++) {
        u32x4 wds;
        wds[0] = cvtpk(sc[kc][ni][0], sc[kc][ni][1]);
        wds[1] = cvtpk(sc[kc][ni][2], sc[kc][ni][3]);
        wds[2] = cvtpk(sc[kc + 2][ni][0], sc[kc + 2][ni][1]);
        wds[3] = cvtpk(sc[kc + 2][ni][2], sc[kc + 2][ni][3]);
        pf[ni][kc] = __builtin_bit_cast(s8v, wds);
      }

    // ---- PV: O^T[d][q] += Vt * P^T ----
    __builtin_amdgcn_s_setprio(1);
    #pragma unroll
    for (int kc = 0; kc < 2; kc++) {
      #pragma unroll
      for (int di = 0; di < 4; di++) {
        s8v vf = *(const s8v*)(Vs + (di * 16 + l16) * PAD + kc * 32 + quad * 8);
        O[di][0] = __builtin_amdgcn_mfma_f32_16x16x32_bf16(vf, pf[0][kc], O[di][0], 0, 0, 0);
        O[di][1] = __builtin_amdgcn_mfma_f32_16x16x32_bf16(vf, pf[1][kc], O[di][1], 0, 0, 0);
      }
    }
    __builtin_amdgcn_s_setprio(0);
  }

  // ---- epilogue: normalize, transpose via LDS (wave-private rows), coalesced write ----
  const float inv0 = 1.f / lrun[0], inv1 = 1.f / lrun[1];
  #pragma unroll
  for (int di = 0; di < 4; di++)
    #pragma unroll
    for (int ni = 0; ni < 2; ni++) {
      const float inv = ni ? inv1 : inv0;
      #pragma unroll
      for (int r = 0; r < 4; r++)
        QPs[(w * 32 + ni * 16 + l16) * PAD + di * 16 + quad * 4 + r] = f2bf1(O[di][ni][r] * inv);
    }
  __syncthreads();
  {
    const int r = t >> 1, c0 = (t & 1) * 32;
    u16* dst = Ob + qkbase + (size_t)(q0 + r) * DIM + c0;
    #pragma unroll
    for (int ch = 0; ch < 4; ch++)
      *(u16x8*)(dst + ch * 8) = *(const u16x8*)(QPs + r * PAD + c0 + ch * 8);
  }
}

// ---------------- launch ----------------
extern "C" void kernel_launch(void* const* d_in, const int* in_sizes, int n_in,
                              void* d_out, int out_size, void* d_ws, size_t ws_size,
                              hipStream_t stream) {
  (void)in_sizes; (void)n_in; (void)out_size; (void)ws_size;
  const float* x  = (const float*)d_in[0];
  const float* Wq = (const float*)d_in[1];
  const float* Wk = (const float*)d_in[2];
  const float* Wv = (const float*)d_in[3];
  const float* Wo = (const float*)d_in[4];
  const float* bo = (const float*)d_in[5];
  float* out = (float*)d_out;

  char* ws = (char*)d_ws;
  const size_t MB = 1024ull * 1024ull;
  u16* Xb  = (u16*)(ws);             // 16 MB: x bf16 [8192][1024]
  u16* Wt  = (u16*)(ws + 16 * MB);   //  8 MB: Wq(scaled),Wk,Wv,Wo transposed bf16
  u16* Qb  = (u16*)(ws + 24 * MB);   // 16 MB
  u16* Kb  = (u16*)(ws + 40 * MB);   // 16 MB
  u16* Vtg = (u16*)(ws + 56 * MB);   // 16 MB: V transposed [b][h][d][s]
  u16* Cb  = (u16*)(ws + 72 * MB);   // 16 MB: ctx -> 88 MB total

  const int NTOK = BSZ * SEQ;  // 8192
  const int n4 = NTOK * DIM / 4;
  cast_bf16_kernel<<<(n4 + 255) / 256, 256, 0, stream>>>(x, Xb, n4);
  transpose_cast_kernel<<<dim3(32, 32, 4), 256, 0, stream>>>(Wq, Wk, Wv, Wo, Wt);

  // 3 * (8192/128) * (1024/128) = 1536 blocks = 2 clean epochs at 3 blocks/CU
  gemm_qkv<<<dim3(1536), 256, 0, stream>>>(Xb, Wt, Qb, Kb, Vtg);

  // unpaired: (NH, 16 q-tiles, BSZ) = 1024 blocks at 3 blocks/CU
  flash_attn_mfma<<<dim3(NH, 16, BSZ), 256, 0, stream>>>(Qb, Kb, Vtg, Cb);

  // (8192/128) * (1024/128) = 512 blocks
  gemm_proj<<<dim3(512), 256, 0, stream>>>(Cb, Wt + 3ull * DIM * DIM, out, bo);
}